// Round 18
// baseline (82.757 us; speedup 1.0000x reference)
//
#include <hip/hip_runtime.h>
#include <stdint.h>

using f32x4  = __attribute__((ext_vector_type(4))) float;
using f32x16 = __attribute__((ext_vector_type(16))) float;
using s16x8  = __attribute__((ext_vector_type(8))) short;
using u16x4  = __attribute__((ext_vector_type(4))) unsigned short;
using u32x4  = __attribute__((ext_vector_type(4))) unsigned int;

typedef __attribute__((address_space(3))) unsigned int lds_u32;
typedef __attribute__((address_space(1))) unsigned int glb_u32;

__device__ __forceinline__ unsigned short f2bf(float f){
  union { float f; unsigned u; } x; x.f = f;
  return (unsigned short)((x.u + 0x7FFFu + ((x.u >> 16) & 1u)) >> 16);
}
__device__ __forceinline__ unsigned cvt_pk(float lo, float hi){
  unsigned r;
  asm("v_cvt_pk_bf16_f32 %0, %1, %2" : "=v"(r) : "v"(lo), "v"(hi));
  return r;
}
__device__ __forceinline__ void plswap(unsigned &a, unsigned &b){
  asm volatile("v_permlane32_swap_b32 %0, %1" : "+v"(a), "+v"(b));
}

#if __has_builtin(__builtin_amdgcn_exp2f)
#define EXP2F(x) __builtin_amdgcn_exp2f(x)
#else
#define EXP2F(x) exp2f(x)
#endif

#define MFMA16(A,B,C) __builtin_amdgcn_mfma_f32_16x16x32_bf16((A),(B),(C),0,0,0)
#define MFMA32(A,B,C) __builtin_amdgcn_mfma_f32_32x32x16_bf16((A),(B),(C),0,0,0)

constexpr int   L      = 2048;
constexpr int   H      = 16;
constexpr int   E      = 64;
constexpr int   HE     = 1024;
constexpr float SCALE  = 0.125f;
constexpr float QSCALE = 0.18033688011112042f;   // 0.125 * log2(e)

// ---------------- prep (merged): f32 [b,s,h,e] -> bf16 fragment-ordered tiles -------
__global__ __launch_bounds__(256)
void prep_kv(const float* __restrict__ Kg, const float* __restrict__ Vg,
             unsigned short* __restrict__ Ko, unsigned short* __restrict__ Vo){
  __shared__ __align__(16) unsigned short t8[4096];
  const int g0 = blockIdx.x;
  const int t  = threadIdx.x;
  if (g0 < 2048){
    const int gid = g0;
    const int jt = gid & 31, bh = gid >> 5;
    const int b = bh >> 4, h = bh & 15;
    const int key6 = t >> 2;
    const int p    = t & 3;
    const int kb = key6 >> 5, k31 = key6 & 31;
    const float* src = Kg + ((size_t)((b*2048 + jt*64 + key6)*16 + h) << 6) + p*16;
    const float4 v0 = *reinterpret_cast<const float4*>(src);
    const float4 v1 = *reinterpret_cast<const float4*>(src + 4);
    const float4 v2 = *reinterpret_cast<const float4*>(src + 8);
    const float4 v3 = *reinterpret_cast<const float4*>(src + 12);
    s16x8 f0, f1;
    f0[0]=(short)f2bf(v0.x); f0[1]=(short)f2bf(v0.y); f0[2]=(short)f2bf(v0.z); f0[3]=(short)f2bf(v0.w);
    f0[4]=(short)f2bf(v1.x); f0[5]=(short)f2bf(v1.y); f0[6]=(short)f2bf(v1.z); f0[7]=(short)f2bf(v1.w);
    f1[0]=(short)f2bf(v2.x); f1[1]=(short)f2bf(v2.y); f1[2]=(short)f2bf(v2.z); f1[3]=(short)f2bf(v2.w);
    f1[4]=(short)f2bf(v3.x); f1[5]=(short)f2bf(v3.y); f1[6]=(short)f2bf(v3.z); f1[7]=(short)f2bf(v3.w);
    const int slot0 = ((kb*4 + p)*2 + 0)*32 + k31;
    *reinterpret_cast<s16x8*>(&t8[slot0*8])      = f0;
    *reinterpret_cast<s16x8*>(&t8[(slot0+32)*8]) = f1;
    __syncthreads();
    unsigned short* dst = Ko + ((size_t)gid << 12) + t*16;
    *reinterpret_cast<s16x8*>(dst)     = *reinterpret_cast<const s16x8*>(&t8[t*16]);
    *reinterpret_cast<s16x8*>(dst + 8) = *reinterpret_cast<const s16x8*>(&t8[t*16 + 8]);
  } else {
    const int gid = g0 - 2048;
    const int jt = gid & 31, bh = gid >> 5;
    const int b = bh >> 4, h = bh & 15;
    const int key6 = t >> 2;
    const int p    = t & 3;
    const int kc = key6 >> 4, h2 = (key6 >> 3) & 1, kr = key6 & 7;
    const float* src = Vg + ((size_t)((b*2048 + jt*64 + key6)*16 + h) << 6) + p*16;
    float vv[16];
    #pragma unroll
    for (int q = 0; q < 4; ++q){
      const float4 v = *reinterpret_cast<const float4*>(src + q*4);
      vv[q*4+0]=v.x; vv[q*4+1]=v.y; vv[q*4+2]=v.z; vv[q*4+3]=v.w;
    }
    #pragma unroll
    for (int j = 0; j < 16; ++j){
      const int e  = p*16 + j;
      const int eb = e >> 5, e31 = e & 31;
      const int slot = ((eb*4 + kc)*2 + h2)*32 + e31;
      t8[slot*8 + kr] = f2bf(vv[j]);
    }
    __syncthreads();
    unsigned short* dst = Vo + ((size_t)gid << 12) + t*16;
    *reinterpret_cast<s16x8*>(dst)     = *reinterpret_cast<const s16x8*>(&t8[t*16]);
    *reinterpret_cast<s16x8*>(dst + 8) = *reinterpret_cast<const s16x8*>(&t8[t*16 + 8]);
  }
}

// ---------------- main: split-K 16-wave blocks -> 32 waves/CU ----------------------
// 1024 threads = 16 waves; block = 256 q-rows of one (b,h). Waves 0-7 (lower group)
// process key tiles [4qb, 16+2qb); waves 8-15 (upper group) tiles [16+2qb, 32) —
// EQUAL counts (16-2qb each) so one shared barrier cadence works. No-max softmax
// makes partials additive: upper passes (acc,l) via LDS, lower adds+normalizes.
// Grid 512 = 2 blocks/CU, balanced (u,u+4) pairing; 8192 waves = 32/CU static.
__global__ __launch_bounds__(1024, 4)
void attn18(const float* __restrict__ Qg, const unsigned short* __restrict__ Kbg,
            const unsigned short* __restrict__ Vtg, float* __restrict__ Og)
{
  __shared__ __align__(16) unsigned char smem[65536];
  unsigned short* KbL = (unsigned short*)(smem);           // [2][4096]
  unsigned short* VbL = (unsigned short*)(smem + 16384);
  unsigned short* KbU = (unsigned short*)(smem + 32768);
  unsigned short* VbU = (unsigned short*)(smem + 49152);

  const int tid  = threadIdx.x;
  const int wave = tid >> 6;        // 0..15
  const int grp  = wave >> 3;       // 0 = lower keys, 1 = upper keys
  const int g    = wave & 7;        // row-group 0..7
  const int lane = tid & 63;
  const int c    = lane & 31;       // q column (and e column for PV)
  const int hi   = lane >> 5;

  const int gid = blockIdx.x;
  const int u   = gid >> 6;                 // 0..7 dispatch group
  const int bh  = gid & 63;
  const int qb  = (u < 4) ? u : (11 - u);   // pairs (0,7),(1,6),(2,5),(3,4)
  const int b = bh >> 4, h = bh & 15;
  const int off = (1 << (h >> 2)) - 1;      // 0,1,3,7

  const int    qrow0 = 256 * qb + g * 32;
  const size_t fbase = (size_t)b * L * HE + (size_t)h * 64;
  const size_t tbase = (size_t)bh * 32;     // in 64-key tile units

  unsigned short* Kmy = grp ? KbU : KbL;
  unsigned short* Vmy = grp ? VbU : VbL;

  // Q fragments (B-operand of S'): lane holds Q[q=c][ec*16 + hi*8 + j], QSCALE folded
  s16x8 qf[4];
  {
    const float* qp_ = Qg + fbase + (size_t)(qrow0 + c) * HE;
    #pragma unroll
    for (int ec = 0; ec < 4; ++ec){
      const float4 a  = *reinterpret_cast<const float4*>(qp_ + ec*16 + hi*8);
      const float4 b2 = *reinterpret_cast<const float4*>(qp_ + ec*16 + hi*8 + 4);
      s16x8 v;
      v[0]=(short)f2bf(a.x*QSCALE);  v[1]=(short)f2bf(a.y*QSCALE);
      v[2]=(short)f2bf(a.z*QSCALE);  v[3]=(short)f2bf(a.w*QSCALE);
      v[4]=(short)f2bf(b2.x*QSCALE); v[5]=(short)f2bf(b2.y*QSCALE);
      v[6]=(short)f2bf(b2.z*QSCALE); v[7]=(short)f2bf(b2.w*QSCALE);
      qf[ec] = v;
    }
  }

  s16x8 ones;
  #pragma unroll
  for (int j = 0; j < 8; ++j) ones[j] = (short)0x3F80;   // bf16 1.0

  f32x16 acc0, acc1, accl;
  #pragma unroll
  for (int r = 0; r < 16; ++r){ acc0[r]=0.f; acc1[r]=0.f; accl[r]=0.f; }

  const int niter  = 16 - 2*qb;             // tiles per group (even, >= 2)
  const int tbase0 = grp ? (16 + 2*qb) : (4*qb);
  const int qlim   = qrow0 + c + off;

  // each wave stages 1KB of K + 1KB of V (1/8 of its group's 8KB tiles) -> 2 loads
  auto STAGE = [&](int tl, int nb){
    const unsigned short* gk = Kbg + ((size_t)(tbase + tl) << 12) + (size_t)(g*512 + lane*8);
    const unsigned short* gv = Vtg + ((size_t)(tbase + tl) << 12) + (size_t)(g*512 + lane*8);
    __builtin_amdgcn_global_load_lds((const glb_u32*)gk,
        (lds_u32*)(Kmy + nb*4096 + g*512), 16, 0, 0);
    __builtin_amdgcn_global_load_lds((const glb_u32*)gv,
        (lds_u32*)(Vmy + nb*4096 + g*512), 16, 0, 0);
  };

  auto COMP = [&](int tl, int nb){
    const int s0 = tl * 64;
    const bool last = (tl == 31);
    if (!last && (s0 + 63 <= qrow0 + off)) return;   // sub-tile dead for this wave
    const unsigned short* KB = Kmy + nb*4096;
    const unsigned short* VB = Vmy + nb*4096;

    f32x16 S0, S1;
    #pragma unroll
    for (int r = 0; r < 16; ++r){ S0[r]=0.f; S1[r]=0.f; }
    __builtin_amdgcn_s_setprio(1);
    #pragma unroll
    for (int ec = 0; ec < 4; ++ec){
      const s16x8 k0 = *reinterpret_cast<const s16x8*>(&KB[(((0*4+ec)*2+hi)*32 + c)*8]);
      const s16x8 k1 = *reinterpret_cast<const s16x8*>(&KB[(((1*4+ec)*2+hi)*32 + c)*8]);
      S0 = MFMA32(k0, qf[ec], S0);
      S1 = MFMA32(k1, qf[ec], S1);
    }
    __builtin_amdgcn_s_setprio(0);

    if (last || (s0 <= qrow0 + 31 + off)){
      #pragma unroll
      for (int r = 0; r < 16; ++r){
        const int kg0 = s0 + (r&3) + 8*(r>>2) + 4*hi;
        const int kg1 = kg0 + 32;
        if (!((kg0 > qlim) || (kg0 == L-1))) S0[r] = -1e30f;
        if (!((kg1 > qlim) || (kg1 == L-1))) S1[r] = -1e30f;
      }
    }

    #pragma unroll
    for (int r = 0; r < 16; ++r){
      S0[r] = EXP2F(S0[r]);
      S1[r] = EXP2F(S1[r]);
    }

    __builtin_amdgcn_s_setprio(1);
    #define PV_STEP(Pv, kh, kcg) { \
      unsigned a0 = cvt_pk(Pv[8*(kh)+0], Pv[8*(kh)+1]); \
      unsigned a1 = cvt_pk(Pv[8*(kh)+2], Pv[8*(kh)+3]); \
      unsigned b0 = cvt_pk(Pv[8*(kh)+4], Pv[8*(kh)+5]); \
      unsigned b1 = cvt_pk(Pv[8*(kh)+6], Pv[8*(kh)+7]); \
      plswap(a0, b0); plswap(a1, b1); \
      u32x4 afu; afu[0]=a0; afu[1]=a1; afu[2]=b0; afu[3]=b1; \
      const s16x8 af = __builtin_bit_cast(s16x8, afu); \
      const s16x8 vf0 = *reinterpret_cast<const s16x8*>(&VB[(((0*4+(kcg))*2+hi)*32 + c)*8]); \
      const s16x8 vf1 = *reinterpret_cast<const s16x8*>(&VB[(((1*4+(kcg))*2+hi)*32 + c)*8]); \
      acc0 = MFMA32(af, vf0, acc0); \
      acc1 = MFMA32(af, vf1, acc1); \
      accl = MFMA32(af, ones, accl); \
    }
    PV_STEP(S0, 0, 0)
    PV_STEP(S0, 1, 1)
    PV_STEP(S1, 0, 2)
    PV_STEP(S1, 1, 3)
    #undef PV_STEP
    __builtin_amdgcn_s_setprio(0);
  };

  #define WAITBAR2 asm volatile("s_waitcnt vmcnt(2)\n\ts_barrier" ::: "memory")
  #define WAITBAR0 asm volatile("s_waitcnt vmcnt(0)\n\ts_barrier" ::: "memory")
  #define BARRIER  __builtin_amdgcn_s_barrier()

  STAGE(tbase0 + 0, 0);
  STAGE(tbase0 + 1, 1);

  for (int i = 0; i + 2 < niter; ++i){
    WAITBAR2;               // tile i landed (all 16 waves, both groups)
    COMP(tbase0 + i, i & 1);
    BARRIER;                // all waves done reading buf (i&1)
    STAGE(tbase0 + i + 2, i & 1);
  }
  WAITBAR2;                 // tile niter-2 landed
  COMP(tbase0 + niter - 2, 0);   // niter even -> parity 0
  WAITBAR0;                 // tile niter-1 landed
  COMP(tbase0 + niter - 1, 1);

  #undef WAITBAR2
  #undef WAITBAR0
  #undef BARRIER

  // ---- combine: upper partials -> LDS (33-stride, conflict-free), lower adds ----
  __syncthreads();          // all COMP LDS reads done; staging buffers reusable
  float* accArea = (float*)smem;                 // 4 slots x 64 lanes x 33 floats
  float* lArea   = (float*)(smem + 4*64*33*4);   // 4 slots x 32 floats
  #pragma unroll
  for (int phase = 0; phase < 2; ++phase){
    const int gl = phase*4;
    if (grp == 1 && g >= gl && g < gl+4){
      float* A = accArea + (g-gl)*(64*33) + lane*33;
      #pragma unroll
      for (int r = 0; r < 16; ++r){ A[r] = acc0[r]; A[16+r] = acc1[r]; }
      if (c == 0){
        float* Lp = lArea + (g-gl)*32 + hi*16;
        #pragma unroll
        for (int r = 0; r < 16; ++r) Lp[r] = accl[r];
      }
    }
    __syncthreads();
    if (grp == 0 && g >= gl && g < gl+4){
      const float* A  = accArea + (g-gl)*(64*33) + lane*33;
      const float* Lp = lArea + (g-gl)*32 + hi*16;
      #pragma unroll
      for (int r = 0; r < 16; ++r){
        const float li = 1.0f / (accl[r] + Lp[r]);
        const int rowr = (r&3) + 8*(r>>2) + 4*hi;
        float* op = Og + fbase + (size_t)(qrow0 + rowr) * HE;
        op[c]      = (acc0[r] + A[r])    * li;
        op[32 + c] = (acc1[r] + A[16+r]) * li;
      }
    }
    __syncthreads();
  }
}

// ---------------- fallback (no-ws path, round-1 kernel) ----------------
__global__ __launch_bounds__(512)
void attn_band(const float* __restrict__ Qg, const float* __restrict__ Kg,
               const float* __restrict__ Vg, float* __restrict__ Og)
{
  __shared__ __align__(16) unsigned short Ks[64*64];
  __shared__ __align__(16) unsigned short Vs[64*64];
  __shared__ __align__(16) unsigned short Ps[8][16*64];
  const int tid  = threadIdx.x;
  const int wave = tid >> 6;
  const int lane = tid & 63;
  const int lo16 = lane & 15;
  const int hi4  = lane >> 4;
  const int gid = blockIdx.x;
  const int qb  = gid & 15;
  const int bh  = gid >> 4;
  const int b   = bh >> 4;
  const int h   = bh & 15;
  const int off = (1 << (h >> 2)) - 1;
  const int    r0   = qb * 128;
  const size_t base = (size_t)b * L * HE + (size_t)h * 64;
  const int qrow0 = r0 + wave * 16;
  s16x8 qf[2];
  {
    const float* qp = Qg + base + (size_t)(qrow0 + lo16) * HE;
    #pragma unroll
    for (int ec = 0; ec < 2; ++ec){
      const int e0 = ec*32 + hi4*8;
      s16x8 v;
      #pragma unroll
      for (int j = 0; j < 8; ++j) v[j] = (short)f2bf(qp[e0 + j]);
      qf[ec] = v;
    }
  }
  f32x4 acc[4];
  #pragma unroll
  for (int et = 0; et < 4; ++et) acc[et] = f32x4{0.f,0.f,0.f,0.f};
  float m_run[4], l_run[4];
  #pragma unroll
  for (int i = 0; i < 4; ++i){ m_run[i] = -1e30f; l_run[i] = 0.f; }
  const int j0 = (r0 + off + 1) >> 6;
  for (int jt = j0; jt < 32; ++jt){
    const int s0 = jt * 64;
    __syncthreads();
    {
      const int f4    = tid & 15;
      const int rbase = tid >> 4;
      #pragma unroll
      for (int p = 0; p < 2; ++p){
        const int row = p*32 + rbase;
        const float4 vv = *reinterpret_cast<const float4*>(
            Kg + base + (size_t)(s0 + row) * HE + f4*4);
        u16x4 w; w[0]=f2bf(vv.x); w[1]=f2bf(vv.y); w[2]=f2bf(vv.z); w[3]=f2bf(vv.w);
        const int idx = row*64 + ((f4*4) ^ ((row & 7) << 3));
        *reinterpret_cast<u16x4*>(&Ks[idx]) = w;
      }
    }
    {
      const int kb = tid >> 5;
      const int e0 = (tid & 31) * 2;
      float2 cc[4];
      #pragma unroll
      for (int j = 0; j < 4; ++j)
        cc[j] = *reinterpret_cast<const float2*>(
            Vg + base + (size_t)(s0 + 4*kb + j) * HE + e0);
      #pragma unroll
      for (int i = 0; i < 2; ++i){
        const int e = e0 + i;
        u16x4 w;
        w[0] = f2bf(i ? cc[0].y : cc[0].x);
        w[1] = f2bf(i ? cc[1].y : cc[1].x);
        w[2] = f2bf(i ? cc[2].y : cc[2].x);
        w[3] = f2bf(i ? cc[3].y : cc[3].x);
        const int idx = e*64 + ((kb*4) ^ ((e & 7) << 3));
        *reinterpret_cast<u16x4*>(&Vs[idx]) = w;
      }
    }
    __syncthreads();
    if (jt < 31 && s0 + 63 <= qrow0 + off) continue;
    f32x4 S[4];
    #pragma unroll
    for (int kt = 0; kt < 4; ++kt){
      const int key = kt*16 + lo16;
      f32x4 z = {0.f,0.f,0.f,0.f};
      #pragma unroll
      for (int ec = 0; ec < 2; ++ec){
        const int e = ec*32 + hi4*8;
        const s16x8 kf = *reinterpret_cast<const s16x8*>(
            &Ks[key*64 + (e ^ ((key & 7) << 3))]);
        z = MFMA16(qf[ec], kf, z);
      }
      S[kt] = z;
    }
    #pragma unroll
    for (int kt = 0; kt < 4; ++kt){
      const int kg = s0 + kt*16 + lo16;
      #pragma unroll
      for (int i = 0; i < 4; ++i){
        const int qg2 = qrow0 + hi4*4 + i;
        const bool ok = (kg > qg2 + off) || (kg == L-1);
        S[kt][i] = ok ? S[kt][i]*SCALE : -1e30f;
      }
    }
    #pragma unroll
    for (int i = 0; i < 4; ++i){
      float t = fmaxf(fmaxf(S[0][i],S[1][i]), fmaxf(S[2][i],S[3][i]));
      t = fmaxf(t, __shfl_xor(t,1));
      t = fmaxf(t, __shfl_xor(t,2));
      t = fmaxf(t, __shfl_xor(t,4));
      t = fmaxf(t, __shfl_xor(t,8));
      const float mn = fmaxf(m_run[i], t);
      const float rs = __expf(m_run[i] - mn);
      m_run[i]  = mn;
      l_run[i] *= rs;
      acc[0][i] *= rs; acc[1][i] *= rs; acc[2][i] *= rs; acc[3][i] *= rs;
    }
    unsigned short* pwv = Ps[wave];
    float rsum[4] = {0.f,0.f,0.f,0.f};
    #pragma unroll
    for (int kt = 0; kt < 4; ++kt){
      #pragma unroll
      for (int i = 0; i < 4; ++i){
        const float p = __expf(S[kt][i] - m_run[i]);
        rsum[i] += p;
        const int qr  = hi4*4 + i;
        const int col = kt*16 + lo16;
        pwv[qr*64 + (col ^ ((qr & 7) << 3))] = f2bf(p);
      }
    }
    #pragma unroll
    for (int i = 0; i < 4; ++i){
      float t = rsum[i];
      t += __shfl_xor(t,1); t += __shfl_xor(t,2);
      t += __shfl_xor(t,4); t += __shfl_xor(t,8);
      l_run[i] += t;
    }
    #pragma unroll
    for (int kc = 0; kc < 2; ++kc){
      const int kk = kc*32 + hi4*8;
      const s16x8 pf = *reinterpret_cast<const s16x8*>(
          &pwv[lo16*64 + (kk ^ ((lo16 & 7) << 3))]);
      #pragma unroll
      for (int et = 0; et < 4; ++et){
        const int e = et*16 + lo16;
        const s16x8 vf = *reinterpret_cast<const s16x8*>(
            &Vs[e*64 + (kk ^ ((e & 7) << 3))]);
        acc[et] = MFMA16(pf, vf, acc[et]);
      }
    }
  }
  #pragma unroll
  for (int i = 0; i < 4; ++i){
    const float inv = 1.0f / l_run[i];
    const int   qg2 = qrow0 + hi4*4 + i;
    float* op = Og + base + (size_t)qg2 * HE;
    #pragma unroll
    for (int et = 0; et < 4; ++et)
      op[et*16 + lo16] = acc[et][i] * inv;
  }
}

extern "C" void kernel_launch(void* const* d_in, const int* in_sizes, int n_in,
                              void* d_out, int out_size, void* d_ws, size_t ws_size,
                              hipStream_t stream) {
  const float* Q = (const float*)d_in[0];
  const float* K = (const float*)d_in[1];
  const float* V = (const float*)d_in[2];
  float* O = (float*)d_out;

  const size_t kb_bytes = (size_t)64 * 32 * 4096 * 2;   // 16 MB per tensor
  const size_t need     = kb_bytes * 2;                 // 32 MB
  if (ws_size >= need) {
    unsigned short* Kb = (unsigned short*)d_ws;
    unsigned short* Vt = (unsigned short*)((char*)d_ws + kb_bytes);
    prep_kv<<<dim3(4096), dim3(256), 0, stream>>>(K, V, Kb, Vt);
    attn18 <<<dim3(512),  dim3(1024), 0, stream>>>(Q, Kb, Vt, O);
  } else {
    attn_band<<<dim3(1024), dim3(512), 0, stream>>>(Q, K, V, O);
  }
}

// Round 20
// 70.788 us; speedup vs baseline: 1.1691x; 1.1691x over previous
//
#include <hip/hip_runtime.h>
#include <stdint.h>

using f32x4  = __attribute__((ext_vector_type(4))) float;
using f32x16 = __attribute__((ext_vector_type(16))) float;
using s16x8  = __attribute__((ext_vector_type(8))) short;
using u16x4  = __attribute__((ext_vector_type(4))) unsigned short;
using u32x4  = __attribute__((ext_vector_type(4))) unsigned int;

typedef __attribute__((address_space(3))) unsigned int lds_u32;
typedef __attribute__((address_space(1))) unsigned int glb_u32;

__device__ __forceinline__ unsigned short f2bf(float f){
  union { float f; unsigned u; } x; x.f = f;
  return (unsigned short)((x.u + 0x7FFFu + ((x.u >> 16) & 1u)) >> 16);
}
__device__ __forceinline__ unsigned cvt_pk(float lo, float hi){
  unsigned r;
  asm("v_cvt_pk_bf16_f32 %0, %1, %2" : "=v"(r) : "v"(lo), "v"(hi));
  return r;
}
__device__ __forceinline__ void plswap(unsigned &a, unsigned &b){
  asm volatile("v_permlane32_swap_b32 %0, %1" : "+v"(a), "+v"(b));
}

#if __has_builtin(__builtin_amdgcn_exp2f)
#define EXP2F(x) __builtin_amdgcn_exp2f(x)
#else
#define EXP2F(x) exp2f(x)
#endif

#define MFMA16(A,B,C) __builtin_amdgcn_mfma_f32_16x16x32_bf16((A),(B),(C),0,0,0)
#define MFMA32(A,B,C) __builtin_amdgcn_mfma_f32_32x32x16_bf16((A),(B),(C),0,0,0)

constexpr int   L      = 2048;
constexpr int   H      = 16;
constexpr int   E      = 64;
constexpr int   HE     = 1024;
constexpr float SCALE  = 0.125f;
constexpr float QSCALE = 0.18033688011112042f;   // 0.125 * log2(e)

// ---------------- prep (merged): f32 [b,s,h,e] -> bf16 fragment-ordered tiles -------
// gid < 2048: K tile (bh,jt64): slot = ((kb*4+ec)*2+hi)*32 + k31 -> K[...][ec*16+hi*8..+8)
// gid >=2048: V tile (bh,jt64): slot = ((eb*4+kc)*2+h2)*32 + e31 -> V^T 8-key sliver
__global__ __launch_bounds__(256)
void prep_kv(const float* __restrict__ Kg, const float* __restrict__ Vg,
             unsigned short* __restrict__ Ko, unsigned short* __restrict__ Vo){
  __shared__ __align__(16) unsigned short t8[4096];
  const int g0 = blockIdx.x;
  const int t  = threadIdx.x;
  if (g0 < 2048){
    const int gid = g0;
    const int jt = gid & 31, bh = gid >> 5;
    const int b = bh >> 4, h = bh & 15;
    const int key6 = t >> 2;
    const int p    = t & 3;
    const int kb = key6 >> 5, k31 = key6 & 31;
    const float* src = Kg + ((size_t)((b*2048 + jt*64 + key6)*16 + h) << 6) + p*16;
    const float4 v0 = *reinterpret_cast<const float4*>(src);
    const float4 v1 = *reinterpret_cast<const float4*>(src + 4);
    const float4 v2 = *reinterpret_cast<const float4*>(src + 8);
    const float4 v3 = *reinterpret_cast<const float4*>(src + 12);
    s16x8 f0, f1;
    f0[0]=(short)f2bf(v0.x); f0[1]=(short)f2bf(v0.y); f0[2]=(short)f2bf(v0.z); f0[3]=(short)f2bf(v0.w);
    f0[4]=(short)f2bf(v1.x); f0[5]=(short)f2bf(v1.y); f0[6]=(short)f2bf(v1.z); f0[7]=(short)f2bf(v1.w);
    f1[0]=(short)f2bf(v2.x); f1[1]=(short)f2bf(v2.y); f1[2]=(short)f2bf(v2.z); f1[3]=(short)f2bf(v2.w);
    f1[4]=(short)f2bf(v3.x); f1[5]=(short)f2bf(v3.y); f1[6]=(short)f2bf(v3.z); f1[7]=(short)f2bf(v3.w);
    const int slot0 = ((kb*4 + p)*2 + 0)*32 + k31;
    *reinterpret_cast<s16x8*>(&t8[slot0*8])      = f0;
    *reinterpret_cast<s16x8*>(&t8[(slot0+32)*8]) = f1;
    __syncthreads();
    unsigned short* dst = Ko + ((size_t)gid << 12) + t*16;
    *reinterpret_cast<s16x8*>(dst)     = *reinterpret_cast<const s16x8*>(&t8[t*16]);
    *reinterpret_cast<s16x8*>(dst + 8) = *reinterpret_cast<const s16x8*>(&t8[t*16 + 8]);
  } else {
    const int gid = g0 - 2048;
    const int jt = gid & 31, bh = gid >> 5;
    const int b = bh >> 4, h = bh & 15;
    const int key6 = t >> 2;
    const int p    = t & 3;
    const int kc = key6 >> 4, h2 = (key6 >> 3) & 1, kr = key6 & 7;
    const float* src = Vg + ((size_t)((b*2048 + jt*64 + key6)*16 + h) << 6) + p*16;
    float vv[16];
    #pragma unroll
    for (int q = 0; q < 4; ++q){
      const float4 v = *reinterpret_cast<const float4*>(src + q*4);
      vv[q*4+0]=v.x; vv[q*4+1]=v.y; vv[q*4+2]=v.z; vv[q*4+3]=v.w;
    }
    #pragma unroll
    for (int j = 0; j < 16; ++j){
      const int e  = p*16 + j;
      const int eb = e >> 5, e31 = e & 31;
      const int slot = ((eb*4 + kc)*2 + h2)*32 + e31;
      t8[slot*8 + kr] = f2bf(vv[j]);
    }
    __syncthreads();
    unsigned short* dst = Vo + ((size_t)gid << 12) + t*16;
    *reinterpret_cast<s16x8*>(dst)     = *reinterpret_cast<const s16x8*>(&t8[t*16]);
    *reinterpret_cast<s16x8*>(dst + 8) = *reinterpret_cast<const s16x8*>(&t8[t*16 + 8]);
  }
}

// ---------------- main: attn13 structure with KVBLK=128 (two 64-key sub-tiles) ------
// 512 threads = 8 waves; block = 256 contiguous q-rows; wave = 32 rows. Grid = 512,
// balanced pairing (u, u+4) -> per-CU pair sums equal. Each pipeline step stages a
// 128-key tile (32KB K+V) and computes two independent 64-key sub-tiles -> half the
// barriers/vmcnt waits per key, ~2x per-wave ILP (QK(sub1) overlaps PV(sub0)).
__global__ __launch_bounds__(512, 4)
void attn14(const float* __restrict__ Qg, const unsigned short* __restrict__ Kbg,
            const unsigned short* __restrict__ Vtg, float* __restrict__ Og)
{
  __shared__ __align__(16) unsigned short Kbuf[2][8192];
  __shared__ __align__(16) unsigned short Vbuf[2][8192];

  const int tid  = threadIdx.x;
  const int wave = tid >> 6;        // 0..7
  const int lane = tid & 63;
  const int c    = lane & 31;       // q column (and e column for PV)
  const int hi   = lane >> 5;

  const int gid = blockIdx.x;
  const int u   = gid >> 6;                 // 0..7 dispatch group
  const int bh  = gid & 63;
  const int qb  = (u < 4) ? u : (11 - u);   // pairs (0,7),(1,6),(2,5),(3,4)
  const int b = bh >> 4, h = bh & 15;
  const int off = (1 << (h >> 2)) - 1;      // 0,1,3,7

  const int    qrow0 = 256 * qb + wave * 32;
  const size_t fbase = (size_t)b * L * HE + (size_t)h * 64;
  const size_t tbase = (size_t)bh * 32;     // in 64-key tile units

  // Q fragments (B-operand of S'): lane holds Q[q=c][ec*16 + hi*8 + j], QSCALE folded
  s16x8 qf[4];
  {
    const float* qp_ = Qg + fbase + (size_t)(qrow0 + c) * HE;
    #pragma unroll
    for (int ec = 0; ec < 4; ++ec){
      const float4 a  = *reinterpret_cast<const float4*>(qp_ + ec*16 + hi*8);
      const float4 b2 = *reinterpret_cast<const float4*>(qp_ + ec*16 + hi*8 + 4);
      s16x8 v;
      v[0]=(short)f2bf(a.x*QSCALE);  v[1]=(short)f2bf(a.y*QSCALE);
      v[2]=(short)f2bf(a.z*QSCALE);  v[3]=(short)f2bf(a.w*QSCALE);
      v[4]=(short)f2bf(b2.x*QSCALE); v[5]=(short)f2bf(b2.y*QSCALE);
      v[6]=(short)f2bf(b2.z*QSCALE); v[7]=(short)f2bf(b2.w*QSCALE);
      qf[ec] = v;
    }
  }

  s16x8 ones;
  #pragma unroll
  for (int j = 0; j < 8; ++j) ones[j] = (short)0x3F80;   // bf16 1.0

  f32x16 acc0, acc1, accl;
  #pragma unroll
  for (int r = 0; r < 16; ++r){ acc0[r]=0.f; acc1[r]=0.f; accl[r]=0.f; }

  const int j0   = 2 * qb;                  // first live 128-key tile (even, 0..14)
  const int qlim = qrow0 + c + off;

  // stage one 128-key tile (= two consecutive 64-key scratch tiles, 16KB K + 16KB V);
  // wave w moves 2KB of K + 2KB of V -> 4 global_load_lds per wave
  auto STAGE = [&](int jt, int nb){
    const unsigned short* gk = Kbg + ((size_t)(tbase + 2*jt) << 12) + (size_t)(wave*1024 + lane*8);
    const unsigned short* gv = Vtg + ((size_t)(tbase + 2*jt) << 12) + (size_t)(wave*1024 + lane*8);
    __builtin_amdgcn_global_load_lds((const glb_u32*)gk,
        (lds_u32*)&Kbuf[nb][wave*1024], 16, 0, 0);
    __builtin_amdgcn_global_load_lds((const glb_u32*)(gk + 512),
        (lds_u32*)&Kbuf[nb][wave*1024 + 512], 16, 0, 0);
    __builtin_amdgcn_global_load_lds((const glb_u32*)gv,
        (lds_u32*)&Vbuf[nb][wave*1024], 16, 0, 0);
    __builtin_amdgcn_global_load_lds((const glb_u32*)(gv + 512),
        (lds_u32*)&Vbuf[nb][wave*1024 + 512], 16, 0, 0);
  };

  // one 64-key sub-tile (original attn13 body)
  auto SUB = [&](int s0, bool last, const unsigned short* KB, const unsigned short* VB){
    if (!last && (s0 + 63 <= qrow0 + off)) return;   // sub-tile dead for this wave

    f32x16 S0, S1;
    #pragma unroll
    for (int r = 0; r < 16; ++r){ S0[r]=0.f; S1[r]=0.f; }
    __builtin_amdgcn_s_setprio(1);
    #pragma unroll
    for (int ec = 0; ec < 4; ++ec){
      const s16x8 k0 = *reinterpret_cast<const s16x8*>(&KB[(((0*4+ec)*2+hi)*32 + c)*8]);
      const s16x8 k1 = *reinterpret_cast<const s16x8*>(&KB[(((1*4+ec)*2+hi)*32 + c)*8]);
      S0 = MFMA32(k0, qf[ec], S0);
      S1 = MFMA32(k1, qf[ec], S1);
    }
    __builtin_amdgcn_s_setprio(0);

    if (last || (s0 <= qrow0 + 31 + off)){
      #pragma unroll
      for (int r = 0; r < 16; ++r){
        const int kg0 = s0 + (r&3) + 8*(r>>2) + 4*hi;
        const int kg1 = kg0 + 32;
        if (!((kg0 > qlim) || (kg0 == L-1))) S0[r] = -1e30f;
        if (!((kg1 > qlim) || (kg1 == L-1))) S1[r] = -1e30f;
      }
    }

    #pragma unroll
    for (int r = 0; r < 16; ++r){
      S0[r] = EXP2F(S0[r]);
      S1[r] = EXP2F(S1[r]);
    }

    __builtin_amdgcn_s_setprio(1);
    #define PV_STEP(Pv, kh, kcg) { \
      unsigned a0 = cvt_pk(Pv[8*(kh)+0], Pv[8*(kh)+1]); \
      unsigned a1 = cvt_pk(Pv[8*(kh)+2], Pv[8*(kh)+3]); \
      unsigned b0 = cvt_pk(Pv[8*(kh)+4], Pv[8*(kh)+5]); \
      unsigned b1 = cvt_pk(Pv[8*(kh)+6], Pv[8*(kh)+7]); \
      plswap(a0, b0); plswap(a1, b1); \
      u32x4 afu; afu[0]=a0; afu[1]=a1; afu[2]=b0; afu[3]=b1; \
      const s16x8 af = __builtin_bit_cast(s16x8, afu); \
      const s16x8 vf0 = *reinterpret_cast<const s16x8*>(&VB[(((0*4+(kcg))*2+hi)*32 + c)*8]); \
      const s16x8 vf1 = *reinterpret_cast<const s16x8*>(&VB[(((1*4+(kcg))*2+hi)*32 + c)*8]); \
      acc0 = MFMA32(af, vf0, acc0); \
      acc1 = MFMA32(af, vf1, acc1); \
      accl = MFMA32(af, ones, accl); \
    }
    PV_STEP(S0, 0, 0)
    PV_STEP(S0, 1, 1)
    PV_STEP(S1, 0, 2)
    PV_STEP(S1, 1, 3)
    #undef PV_STEP
    __builtin_amdgcn_s_setprio(0);
  };

  auto COMP = [&](int jt, int nb){
    const int s0 = jt * 128;
    if ((jt < 15) && (s0 + 127 <= qrow0 + off)) return;  // whole tile dead
    SUB(s0,      false,        &Kbuf[nb][0],    &Vbuf[nb][0]);
    SUB(s0 + 64, (jt == 15),   &Kbuf[nb][4096], &Vbuf[nb][4096]);
  };

  #define WAITBAR4 asm volatile("s_waitcnt vmcnt(4)\n\ts_barrier" ::: "memory")
  #define WAITBAR0 asm volatile("s_waitcnt vmcnt(0)\n\ts_barrier" ::: "memory")
  #define BARRIER  __builtin_amdgcn_s_barrier()

  STAGE(j0, 0);
  if (j0 + 1 < 16) STAGE(j0 + 1, 1);

  // single-step pipeline over 128-key tiles, buffers by tile parity (j0 even)
  for (int jt = j0; jt < 14; ++jt){
    WAITBAR4;               // tile jt landed (all 8 waves)
    COMP(jt, jt & 1);
    BARRIER;                // all waves done reading buf (jt&1)
    STAGE(jt + 2, jt & 1);
  }
  if (j0 < 15){
    WAITBAR4;               // tile 14 landed
    COMP(14, 0);
  }
  WAITBAR0;                 // tile 15 landed
  COMP(15, 1);

  #undef WAITBAR4
  #undef WAITBAR0
  #undef BARRIER

  // epilogue: O = acc / l  (accl columns all equal the row-sum of P)
  #pragma unroll
  for (int r = 0; r < 16; ++r){
    const int rowr = (r&3) + 8*(r>>2) + 4*hi;
    const float li = 1.0f / accl[r];
    float* op = Og + fbase + (size_t)(qrow0 + rowr) * HE;
    op[c]      = acc0[r] * li;
    op[32 + c] = acc1[r] * li;
  }
}

// ---------------- fallback (no-ws path, round-1 kernel) ----------------
__global__ __launch_bounds__(512)
void attn_band(const float* __restrict__ Qg, const float* __restrict__ Kg,
               const float* __restrict__ Vg, float* __restrict__ Og)
{
  __shared__ __align__(16) unsigned short Ks[64*64];
  __shared__ __align__(16) unsigned short Vs[64*64];
  __shared__ __align__(16) unsigned short Ps[8][16*64];
  const int tid  = threadIdx.x;
  const int wave = tid >> 6;
  const int lane = tid & 63;
  const int lo16 = lane & 15;
  const int hi4  = lane >> 4;
  const int gid = blockIdx.x;
  const int qb  = gid & 15;
  const int bh  = gid >> 4;
  const int b   = bh >> 4;
  const int h   = bh & 15;
  const int off = (1 << (h >> 2)) - 1;
  const int    r0   = qb * 128;
  const size_t base = (size_t)b * L * HE + (size_t)h * 64;
  const int qrow0 = r0 + wave * 16;
  s16x8 qf[2];
  {
    const float* qp = Qg + base + (size_t)(qrow0 + lo16) * HE;
    #pragma unroll
    for (int ec = 0; ec < 2; ++ec){
      const int e0 = ec*32 + hi4*8;
      s16x8 v;
      #pragma unroll
      for (int j = 0; j < 8; ++j) v[j] = (short)f2bf(qp[e0 + j]);
      qf[ec] = v;
    }
  }
  f32x4 acc[4];
  #pragma unroll
  for (int et = 0; et < 4; ++et) acc[et] = f32x4{0.f,0.f,0.f,0.f};
  float m_run[4], l_run[4];
  #pragma unroll
  for (int i = 0; i < 4; ++i){ m_run[i] = -1e30f; l_run[i] = 0.f; }
  const int j0 = (r0 + off + 1) >> 6;
  for (int jt = j0; jt < 32; ++jt){
    const int s0 = jt * 64;
    __syncthreads();
    {
      const int f4    = tid & 15;
      const int rbase = tid >> 4;
      #pragma unroll
      for (int p = 0; p < 2; ++p){
        const int row = p*32 + rbase;
        const float4 vv = *reinterpret_cast<const float4*>(
            Kg + base + (size_t)(s0 + row) * HE + f4*4);
        u16x4 w; w[0]=f2bf(vv.x); w[1]=f2bf(vv.y); w[2]=f2bf(vv.z); w[3]=f2bf(vv.w);
        const int idx = row*64 + ((f4*4) ^ ((row & 7) << 3));
        *reinterpret_cast<u16x4*>(&Ks[idx]) = w;
      }
    }
    {
      const int kb = tid >> 5;
      const int e0 = (tid & 31) * 2;
      float2 cc[4];
      #pragma unroll
      for (int j = 0; j < 4; ++j)
        cc[j] = *reinterpret_cast<const float2*>(
            Vg + base + (size_t)(s0 + 4*kb + j) * HE + e0);
      #pragma unroll
      for (int i = 0; i < 2; ++i){
        const int e = e0 + i;
        u16x4 w;
        w[0] = f2bf(i ? cc[0].y : cc[0].x);
        w[1] = f2bf(i ? cc[1].y : cc[1].x);
        w[2] = f2bf(i ? cc[2].y : cc[2].x);
        w[3] = f2bf(i ? cc[3].y : cc[3].x);
        const int idx = e*64 + ((kb*4) ^ ((e & 7) << 3));
        *reinterpret_cast<u16x4*>(&Vs[idx]) = w;
      }
    }
    __syncthreads();
    if (jt < 31 && s0 + 63 <= qrow0 + off) continue;
    f32x4 S[4];
    #pragma unroll
    for (int kt = 0; kt < 4; ++kt){
      const int key = kt*16 + lo16;
      f32x4 z = {0.f,0.f,0.f,0.f};
      #pragma unroll
      for (int ec = 0; ec < 2; ++ec){
        const int e = ec*32 + hi4*8;
        const s16x8 kf = *reinterpret_cast<const s16x8*>(
            &Ks[key*64 + (e ^ ((key & 7) << 3))]);
        z = MFMA16(qf[ec], kf, z);
      }
      S[kt] = z;
    }
    #pragma unroll
    for (int kt = 0; kt < 4; ++kt){
      const int kg = s0 + kt*16 + lo16;
      #pragma unroll
      for (int i = 0; i < 4; ++i){
        const int qg2 = qrow0 + hi4*4 + i;
        const bool ok = (kg > qg2 + off) || (kg == L-1);
        S[kt][i] = ok ? S[kt][i]*SCALE : -1e30f;
      }
    }
    #pragma unroll
    for (int i = 0; i < 4; ++i){
      float t = fmaxf(fmaxf(S[0][i],S[1][i]), fmaxf(S[2][i],S[3][i]));
      t = fmaxf(t, __shfl_xor(t,1));
      t = fmaxf(t, __shfl_xor(t,2));
      t = fmaxf(t, __shfl_xor(t,4));
      t = fmaxf(t, __shfl_xor(t,8));
      const float mn = fmaxf(m_run[i], t);
      const float rs = __expf(m_run[i] - mn);
      m_run[i]  = mn;
      l_run[i] *= rs;
      acc[0][i] *= rs; acc[1][i] *= rs; acc[2][i] *= rs; acc[3][i] *= rs;
    }
    unsigned short* pwv = Ps[wave];
    float rsum[4] = {0.f,0.f,0.f,0.f};
    #pragma unroll
    for (int kt = 0; kt < 4; ++kt){
      #pragma unroll
      for (int i = 0; i < 4; ++i){
        const float p = __expf(S[kt][i] - m_run[i]);
        rsum[i] += p;
        const int qr  = hi4*4 + i;
        const int col = kt*16 + lo16;
        pwv[qr*64 + (col ^ ((qr & 7) << 3))] = f2bf(p);
      }
    }
    #pragma unroll
    for (int i = 0; i < 4; ++i){
      float t = rsum[i];
      t += __shfl_xor(t,1); t += __shfl_xor(t,2);
      t += __shfl_xor(t,4); t += __shfl_xor(t,8);
      l_run[i] += t;
    }
    #pragma unroll
    for (int kc = 0; kc < 2; ++kc){
      const int kk = kc*32 + hi4*8;
      const s16x8 pf = *reinterpret_cast<const s16x8*>(
          &pwv[lo16*64 + (kk ^ ((lo16 & 7) << 3))]);
      #pragma unroll
      for (int et = 0; et < 4; ++et){
        const int e = et*16 + lo16;
        const s16x8 vf = *reinterpret_cast<const s16x8*>(
            &Vs[e*64 + (kk ^ ((e & 7) << 3))]);
        acc[et] = MFMA16(pf, vf, acc[et]);
      }
    }
  }
  #pragma unroll
  for (int i = 0; i < 4; ++i){
    const float inv = 1.0f / l_run[i];
    const int   qg2 = qrow0 + hi4*4 + i;
    float* op = Og + base + (size_t)qg2 * HE;
    #pragma unroll
    for (int et = 0; et < 4; ++et)
      op[et*16 + lo16] = acc[et][i] * inv;
  }
}

extern "C" void kernel_launch(void* const* d_in, const int* in_sizes, int n_in,
                              void* d_out, int out_size, void* d_ws, size_t ws_size,
                              hipStream_t stream) {
  const float* Q = (const float*)d_in[0];
  const float* K = (const float*)d_in[1];
  const float* V = (const float*)d_in[2];
  float* O = (float*)d_out;

  const size_t kb_bytes = (size_t)64 * 32 * 4096 * 2;   // 16 MB per tensor
  const size_t need     = kb_bytes * 2;                 // 32 MB
  if (ws_size >= need) {
    unsigned short* Kb = (unsigned short*)d_ws;
    unsigned short* Vt = (unsigned short*)((char*)d_ws + kb_bytes);
    prep_kv<<<dim3(4096), dim3(256), 0, stream>>>(K, V, Kb, Vt);
    attn14 <<<dim3(512),  dim3(512), 0, stream>>>(Q, Kb, Vt, O);
  } else {
    attn_band<<<dim3(1024), dim3(512), 0, stream>>>(Q, K, V, O);
  }
}